// Round 9
// baseline (35.216 us; speedup 1.0000x reference)
//
#include <hip/hip_runtime.h>
#include <math.h>

#define BB 64
#define AA 32
#define KK 50
#define DD 128
#define MAX_KP 50
#define EPS_CS 1e-8f
#define NVEC (3 * BB * AA)   // 6144

__device__ __forceinline__ float dot4(float4 a, float4 b) {
    return a.x * b.x + a.y * b.y + a.z * b.z + a.w * b.w;
}

// One 64-lane wave per (tensor, b, a) vector; 2 waves per 128-thread block.
// Gather instruction i loads TWO rows at once via per-lane addresses:
// lanes 0-31 read row idx[2i], lanes 32-63 read row idx[2i+1], 16B/lane
// (global_load_dwordx4, 1KB per instruction). Indices come from scalar
// (SGPR) loads; row select is one v_cndmask. 25 loads/wave for 50 rows.
// Measured: at the memory-service floor (~6.3 TB/s effective) — halving
// instruction count (R4->R5) and raising waves/CU 24->32 (R4) were both 0.
// Block 0 resets the completion counter (plain store; kernel boundary
// publishes it — no fence in the gather hot path, R6 lesson).
__global__ __launch_bounds__(128) void embed_norm_kernel(
    const int* __restrict__ src, const int* __restrict__ pos,
    const int* __restrict__ neg, const float* __restrict__ table,
    float* __restrict__ out, unsigned* __restrict__ cnt)
{
    if (blockIdx.x == 0 && threadIdx.x == 0) cnt[0] = 0u;

    const int vec = __builtin_amdgcn_readfirstlane(
        (blockIdx.x << 1) | (threadIdx.x >> 6));   // 0..6143, wave-uniform
    const int t  = vec >> 11;                      // / (BB*AA = 2048)
    const int ba = vec & 2047;
    const int* idx = ((t == 0) ? src : (t == 1) ? pos : neg) + ba * KK;

    const int lane = threadIdx.x & 63;
    const int half = lane >> 5;                    // 0: even rows, 1: odd rows
    const int slot = lane & 31;                    // float4 slot within the row

    const float4* tab4 = (const float4*)table;
    float4 acc = make_float4(0.f, 0.f, 0.f, 0.f);
    #pragma unroll
    for (int i = 0; i < KK / 2; ++i) {
        const int r0 = idx[2 * i];                 // SGPR (scalar load)
        const int r1 = idx[2 * i + 1];             // SGPR
        const int row = half ? r1 : r0;            // v_cndmask
        const float4 v = tab4[(row << 5) + slot];  // 32-bit offset, 16B/lane
        acc.x += v.x; acc.y += v.y; acc.z += v.z; acc.w += v.w;
    }

    // combine the two half-wave partials (each lane pairs with lane^32)
    acc.x += __shfl_xor(acc.x, 32, 64);
    acc.y += __shfl_xor(acc.y, 32, 64);
    acc.z += __shfl_xor(acc.z, 32, 64);
    acc.w += __shfl_xor(acc.w, 32, 64);

    const float s = 1.0f / MAX_KP;
    acc.x *= s; acc.y *= s; acc.z *= s; acc.w *= s;

    float sq = dot4(acc, acc);
    #pragma unroll
    for (int off = 16; off > 0; off >>= 1) sq += __shfl_xor(sq, off, 64);

    const float inv = 1.0f / fmaxf(sqrtf(sq), EPS_CS);
    acc.x *= inv; acc.y *= inv; acc.z *= inv; acc.w *= inv;

    if (lane < 32)
        ((float4*)out)[(vec << 5) + slot] = acc;
}

// One block per batch (64 blocks x 512 threads). Stages src+pos+neg
// (96 rows, padded to DD+4 -> b128 reads, <=2-way conflicts; 50.6KB LDS),
// computes all 1024 pos and 1024 neg dots (2 j-cols per thread each),
// block max-reduce, softplus -> per_batch[b]. The 64th finishing block
// (one ACQ_REL RMW per block, at exit, after all compute — R6/R7 lesson:
// keep coherence ops off the cached hot path) reduces the 64 losses with
// a fixed xor tree -> out[0]; deterministic whoever wins.
__global__ __launch_bounds__(512) void cosine_loss_kernel(
    const float* __restrict__ embs, float* __restrict__ per_batch,
    unsigned* __restrict__ cnt, float* __restrict__ out)
{
    const int b   = blockIdx.x;          // 0..63
    const int tid = threadIdx.x;         // 0..511

    __shared__ float s_src[AA][DD + 4];
    __shared__ float s_pos[AA][DD + 4];
    __shared__ float s_neg[AA][DD + 4];

    const float4* src4 = (const float4*)(embs + (long)b * AA * DD);
    const float4* pos4 = (const float4*)(embs + (long)(BB + b) * AA * DD);
    const float4* neg4 = (const float4*)(embs + (long)(2 * BB + b) * AA * DD);

    for (int i = tid; i < AA * DD / 4; i += 512) {   // 1024 float4s each
        const int r = i >> 5, c = i & 31;
        *(float4*)&s_src[r][c * 4] = src4[i];
        *(float4*)&s_pos[r][c * 4] = pos4[i];
        *(float4*)&s_neg[r][c * 4] = neg4[i];
    }
    __syncthreads();

    const int i  = tid >> 4;             // 0..31 src row
    const int j0 = tid & 15;             // tgt cols j0, j0+16

    float p0 = 0.f, p1 = 0.f, n0 = 0.f, n1 = 0.f;
    #pragma unroll 8
    for (int d0 = 0; d0 < DD; d0 += 4) {
        const float4 a  = *(const float4*)&s_src[i][d0];
        const float4 pA = *(const float4*)&s_pos[j0][d0];
        const float4 pB = *(const float4*)&s_pos[j0 + 16][d0];
        const float4 nA = *(const float4*)&s_neg[j0][d0];
        const float4 nB = *(const float4*)&s_neg[j0 + 16][d0];
        p0 += dot4(a, pA); p1 += dot4(a, pB);
        n0 += dot4(a, nA); n1 += dot4(a, nB);
    }
    float pmax = fmaxf(p0, p1);
    float nmax = fmaxf(n0, n1);

    #pragma unroll
    for (int off = 32; off > 0; off >>= 1) {
        pmax = fmaxf(pmax, __shfl_xor(pmax, off, 64));
        nmax = fmaxf(nmax, __shfl_xor(nmax, off, 64));
    }
    __shared__ float sp[8], sn[8];
    __shared__ int s_win;
    if ((tid & 63) == 0) { sp[tid >> 6] = pmax; sn[tid >> 6] = nmax; }
    __syncthreads();

    if (tid == 0) {
        float P = sp[0], N = sn[0];
        #pragma unroll
        for (int w = 1; w < 8; ++w) { P = fmaxf(P, sp[w]); N = fmaxf(N, sn[w]); }
        const float x = P - N;
        const float l = (x >= 0.f) ? log1pf(expf(-x)) : (-x + log1pf(expf(x)));
        __hip_atomic_store(&per_batch[b], l, __ATOMIC_RELAXED,
                           __HIP_MEMORY_SCOPE_AGENT);
        const unsigned old = __hip_atomic_fetch_add(
            cnt, 1u, __ATOMIC_ACQ_REL, __HIP_MEMORY_SCOPE_AGENT);
        s_win = (old == BB - 1);
    }
    __syncthreads();
    if (!s_win) return;

    // winner: 64 parallel bypass loads, fixed xor-tree -> mean
    if (tid < BB) {
        float l = __hip_atomic_load(&per_batch[tid], __ATOMIC_ACQUIRE,
                                    __HIP_MEMORY_SCOPE_AGENT);
        #pragma unroll
        for (int off = 32; off > 0; off >>= 1) l += __shfl_xor(l, off, 64);
        if (tid == 0) out[0] = l * (1.0f / BB);
    }
}

extern "C" void kernel_launch(void* const* d_in, const int* in_sizes, int n_in,
                              void* d_out, int out_size, void* d_ws, size_t ws_size,
                              hipStream_t stream) {
    const int*   batch_source = (const int*)d_in[0];
    const int*   pos_result   = (const int*)d_in[1];
    const int*   neg_result   = (const int*)d_in[2];
    const float* emb_table    = (const float*)d_in[3];
    float* out = (float*)d_out;

    float*    embs      = (float*)d_ws;                 // 3*64*32*128 f32 = 3 MB
    float*    per_batch = embs + 3L * BB * AA * DD;     // 64 f32
    unsigned* cnt       = (unsigned*)(per_batch + BB);  // 1 u32

    embed_norm_kernel<<<NVEC / 2, 128, 0, stream>>>(
        batch_source, pos_result, neg_result, emb_table, embs, cnt);
    cosine_loss_kernel<<<BB, 512, 0, stream>>>(embs, per_batch, cnt, out);
}

// Round 10
// 34.464 us; speedup vs baseline: 1.0218x; 1.0218x over previous
//
#include <hip/hip_runtime.h>
#include <math.h>

#define BB 64
#define AA 32
#define KK 50
#define DD 128
#define MAX_KP 50
#define EPS_CS 1e-8f
#define NVEC (3 * BB * AA)   // 6144

__device__ __forceinline__ float dot4(float4 a, float4 b) {
    return a.x * b.x + a.y * b.y + a.z * b.z + a.w * b.w;
}

// One 64-lane wave per (tensor, b, a) vector; 2 waves per 128-thread block.
// Gather instruction i loads TWO rows at once via per-lane addresses:
// lanes 0-31 read row idx[2i], lanes 32-63 read row idx[2i+1], 16B/lane
// (global_load_dwordx4, 1KB per instruction). Indices come from scalar
// (SGPR) loads; row select is one v_cndmask. 25 loads/wave for 50 rows.
// Measured: at the memory-service floor (~6.3 TB/s effective) — halving
// instruction count (R4->R5), 4x TLP (R3), and access width (R1->R4->R5)
// were all ~0. Fusion via agent-scope atomics/fences regressed 4x
// (R2 +7us, R6 +256us, R7 +6us, R9 +1us) — kernel-boundary sync wins.
__global__ __launch_bounds__(128) void embed_norm_kernel(
    const int* __restrict__ src, const int* __restrict__ pos,
    const int* __restrict__ neg, const float* __restrict__ table,
    float* __restrict__ out)
{
    const int vec = __builtin_amdgcn_readfirstlane(
        (blockIdx.x << 1) | (threadIdx.x >> 6));   // 0..6143, wave-uniform
    const int t  = vec >> 11;                      // / (BB*AA = 2048)
    const int ba = vec & 2047;
    const int* idx = ((t == 0) ? src : (t == 1) ? pos : neg) + ba * KK;

    const int lane = threadIdx.x & 63;
    const int half = lane >> 5;                    // 0: even rows, 1: odd rows
    const int slot = lane & 31;                    // float4 slot within the row

    const float4* tab4 = (const float4*)table;
    float4 acc = make_float4(0.f, 0.f, 0.f, 0.f);
    #pragma unroll
    for (int i = 0; i < KK / 2; ++i) {
        const int r0 = idx[2 * i];                 // SGPR (scalar load)
        const int r1 = idx[2 * i + 1];             // SGPR
        const int row = half ? r1 : r0;            // v_cndmask
        const float4 v = tab4[(row << 5) + slot];  // 32-bit offset, 16B/lane
        acc.x += v.x; acc.y += v.y; acc.z += v.z; acc.w += v.w;
    }

    // combine the two half-wave partials (each lane pairs with lane^32)
    acc.x += __shfl_xor(acc.x, 32, 64);
    acc.y += __shfl_xor(acc.y, 32, 64);
    acc.z += __shfl_xor(acc.z, 32, 64);
    acc.w += __shfl_xor(acc.w, 32, 64);

    const float s = 1.0f / MAX_KP;
    acc.x *= s; acc.y *= s; acc.z *= s; acc.w *= s;

    float sq = dot4(acc, acc);
    #pragma unroll
    for (int off = 16; off > 0; off >>= 1) sq += __shfl_xor(sq, off, 64);

    const float inv = 1.0f / fmaxf(sqrtf(sq), EPS_CS);
    acc.x *= inv; acc.y *= inv; acc.z *= inv; acc.w *= inv;

    if (lane < 32)
        ((float4*)out)[(vec << 5) + slot] = acc;
}

// 4 blocks per batch: q = {pos/neg} x {i-half}. Each block stages 16 src rows
// + 32 tgt rows (rows padded to 132 floats -> b128 reads, <=2-way conflicts),
// computes max over its 16x32 dots, writes a partial max.
__global__ __launch_bounds__(256) void cosine_part_kernel(
    const float* __restrict__ embs, float* __restrict__ part /* [BB][4] */)
{
    const int blk = blockIdx.x;          // 0..255
    const int b   = blk >> 2;
    const int q   = blk & 3;
    const int tens  = q >> 1;            // 0 = pos, 1 = neg
    const int ihalf = q & 1;             // which 16 src rows
    const int tid = threadIdx.x;

    __shared__ float s_src[16][DD + 4];
    __shared__ float s_tgt[AA][DD + 4];

    const float4* src4 = (const float4*)(embs + ((long)b * AA + ihalf * 16) * DD);
    const float4* tgt4 = (const float4*)(embs + (long)(BB + tens * BB + b) * AA * DD);

    for (int i = tid; i < 16 * DD / 4; i += 256) {   // 512 float4s
        const int r = i >> 5, c = i & 31;
        *(float4*)&s_src[r][c * 4] = src4[i];
    }
    for (int i = tid; i < AA * DD / 4; i += 256) {   // 1024 float4s
        const int r = i >> 5, c = i & 31;
        *(float4*)&s_tgt[r][c * 4] = tgt4[i];
    }
    __syncthreads();

    const int si = tid >> 4;             // 0..15 src row
    const int j  = tid & 15;             // tgt cols j, j+16

    float d0s = 0.f, d1s = 0.f;
    #pragma unroll 8
    for (int d0 = 0; d0 < DD; d0 += 4) {
        const float4 a  = *(const float4*)&s_src[si][d0];
        const float4 t0 = *(const float4*)&s_tgt[j][d0];
        const float4 t1 = *(const float4*)&s_tgt[j + 16][d0];
        d0s += dot4(a, t0);
        d1s += dot4(a, t1);
    }
    float m = fmaxf(d0s, d1s);

    #pragma unroll
    for (int off = 32; off > 0; off >>= 1) m = fmaxf(m, __shfl_xor(m, off, 64));
    __shared__ float sm[4];
    if ((tid & 63) == 0) sm[tid >> 6] = m;
    __syncthreads();

    if (tid == 0)
        part[blk] = fmaxf(fmaxf(sm[0], sm[1]), fmaxf(sm[2], sm[3]));
}

// One wave: lane b -> loss_b, wave-reduce fixed-order sum -> mean.
__global__ void finalize_kernel(const float* __restrict__ part,
                                float* __restrict__ out)
{
    const int b = threadIdx.x;           // 0..63
    const float P = fmaxf(part[b * 4 + 0], part[b * 4 + 1]);
    const float N = fmaxf(part[b * 4 + 2], part[b * 4 + 3]);
    const float x = P - N;
    float l = (x >= 0.f) ? log1pf(expf(-x)) : (-x + log1pf(expf(x)));
    #pragma unroll
    for (int off = 32; off > 0; off >>= 1) l += __shfl_xor(l, off, 64);
    if (b == 0) out[0] = l * (1.0f / BB);
}

extern "C" void kernel_launch(void* const* d_in, const int* in_sizes, int n_in,
                              void* d_out, int out_size, void* d_ws, size_t ws_size,
                              hipStream_t stream) {
    const int*   batch_source = (const int*)d_in[0];
    const int*   pos_result   = (const int*)d_in[1];
    const int*   neg_result   = (const int*)d_in[2];
    const float* emb_table    = (const float*)d_in[3];
    float* out = (float*)d_out;

    float* embs = (float*)d_ws;                     // 3*64*32*128 f32 = 3 MB
    float* part = embs + 3L * BB * AA * DD;         // 256 f32

    embed_norm_kernel<<<NVEC / 2, 128, 0, stream>>>(
        batch_source, pos_result, neg_result, emb_table, embs);
    cosine_part_kernel<<<4 * BB, 256, 0, stream>>>(embs, part);
    finalize_kernel<<<1, 64, 0, stream>>>(part, out);
}